// Round 6
// baseline (694.371 us; speedup 1.0000x reference)
//
#include <hip/hip_runtime.h>
#include <hip/hip_bf16.h>
#include <math.h>

// Problem constants (B=2, S=2048, D=2048, 32 heads / 8 KV heads, hd=64)
#define S_LEN   2048
#define DMODEL  2048
#define NHEADS  32
#define NKV     8
#define HD      64
#define MTOK    4096   // B * S
#define KVDIM   512    // NKV * HD

typedef short s16x8 __attribute__((ext_vector_type(8)));  // 8 bf16 (doc-verified MFMA frag type)
typedef float f32x4 __attribute__((ext_vector_type(4)));

// bf16 bit helpers (RNE)
__device__ __forceinline__ ushort f2bf(float f) {
    union { float f; uint u; } a; a.f = f;
    return (ushort)((a.u + 0x7fffu + ((a.u >> 16) & 1u)) >> 16);
}
__device__ __forceinline__ float bf2f(ushort h) {
    union { uint u; float f; } a; a.u = ((uint)h) << 16; return a.f;
}

// ---------------------------------------------------------------------------
// Elementwise fp32 -> bf16 hi + bf16 lo (exact residual, RNE). 8 elems/thread.
// Memory-bound; done ONCE per tensor so GEMM inner loops carry no cvt VALU.
// ---------------------------------------------------------------------------
__global__ __launch_bounds__(256) void csplit(const float* __restrict__ src,
                                              ushort* __restrict__ dh,
                                              ushort* __restrict__ dl, int n8) {
    const int i = blockIdx.x * 256 + threadIdx.x;
    if (i >= n8) return;
    float4 a = ((const float4*)src)[2 * i];
    float4 b = ((const float4*)src)[2 * i + 1];
    float f[8] = {a.x, a.y, a.z, a.w, b.x, b.y, b.z, b.w};
    s16x8 h, l;
#pragma unroll
    for (int j = 0; j < 8; ++j) {
        ushort hb = f2bf(f[j]);
        h[j] = (short)hb;
        l[j] = (short)f2bf(f[j] - bf2f(hb));
    }
    ((s16x8*)dh)[i] = h;
    ((s16x8*)dl)[i] = l;
}

// ---------------------------------------------------------------------------
// Split-precision MFMA GEMM on pre-split operands:
// C[M,N](fp32) = (Ah+Al)[M,K] @ (Bh+Bl)[N,K]^T  ~=  AhBh + AhBl + AlBh.
// 128x128 tile, BK=32, 4 waves (2x2), 64x64/wave. Inner loop is pure
// copy/ds_read/MFMA. LDS stride 32 elems (64 B): frag reads spread 8
// dwords/bank (BW floor); staging is byte-linear in tid.
// ---------------------------------------------------------------------------
__global__ __launch_bounds__(256) void gemm_bs(const ushort* __restrict__ Ahg,
                                               const ushort* __restrict__ Alg,
                                               const ushort* __restrict__ Bhg,
                                               const ushort* __restrict__ Blg,
                                               float* __restrict__ C,
                                               int M, int N, int K) {
    __shared__ ushort Ah[128 * 32];
    __shared__ ushort Al[128 * 32];
    __shared__ ushort Bh[128 * 32];
    __shared__ ushort Bl[128 * 32];

    const int tid  = threadIdx.x;
    const int wave = tid >> 6;
    const int lane = tid & 63;
    const int wr   = (wave >> 1) * 64;
    const int wc   = (wave & 1) * 64;
    const int m0   = blockIdx.y * 128;
    const int n0   = blockIdx.x * 128;

    const int srow = tid >> 2;          // 0..63
    const int skq  = (tid & 3) * 8;     // k-octet 0,8,16,24
    const int soff = srow * 32 + skq;   // LDS elem offset (byte tid*16: linear)

    const ushort* pAh = Ahg + (size_t)(m0 + srow) * K + skq;
    const ushort* pAl = Alg + (size_t)(m0 + srow) * K + skq;
    const ushort* pBh = Bhg + (size_t)(n0 + srow) * K + skq;
    const ushort* pBl = Blg + (size_t)(n0 + srow) * K + skq;
    const size_t r64 = (size_t)64 * K;

    const int frow = lane & 15;
    const int fk   = (lane >> 4) * 8;

    f32x4 acc[4][4] = {};

    s16x8 rAh0 = *(const s16x8*)(pAh), rAh1 = *(const s16x8*)(pAh + r64);
    s16x8 rAl0 = *(const s16x8*)(pAl), rAl1 = *(const s16x8*)(pAl + r64);
    s16x8 rBh0 = *(const s16x8*)(pBh), rBh1 = *(const s16x8*)(pBh + r64);
    s16x8 rBl0 = *(const s16x8*)(pBl), rBl1 = *(const s16x8*)(pBl + r64);

    for (int k0 = 0; k0 < K; k0 += 32) {
        __syncthreads();
        *(s16x8*)(Ah + soff) = rAh0;  *(s16x8*)(Ah + soff + 64 * 32) = rAh1;
        *(s16x8*)(Al + soff) = rAl0;  *(s16x8*)(Al + soff + 64 * 32) = rAl1;
        *(s16x8*)(Bh + soff) = rBh0;  *(s16x8*)(Bh + soff + 64 * 32) = rBh1;
        *(s16x8*)(Bl + soff) = rBl0;  *(s16x8*)(Bl + soff + 64 * 32) = rBl1;

        if (k0 + 32 < K) {   // prefetch next K-slab; lands during MFMA phase
            rAh0 = *(const s16x8*)(pAh + k0 + 32); rAh1 = *(const s16x8*)(pAh + r64 + k0 + 32);
            rAl0 = *(const s16x8*)(pAl + k0 + 32); rAl1 = *(const s16x8*)(pAl + r64 + k0 + 32);
            rBh0 = *(const s16x8*)(pBh + k0 + 32); rBh1 = *(const s16x8*)(pBh + r64 + k0 + 32);
            rBl0 = *(const s16x8*)(pBl + k0 + 32); rBl1 = *(const s16x8*)(pBl + r64 + k0 + 32);
        }
        __syncthreads();

        s16x8 ah[4], al[4], bh[4], bl[4];
#pragma unroll
        for (int mi = 0; mi < 4; ++mi) {
            int off = (wr + mi * 16 + frow) * 32 + fk;
            ah[mi] = *(const s16x8*)(Ah + off);
            al[mi] = *(const s16x8*)(Al + off);
        }
#pragma unroll
        for (int nj = 0; nj < 4; ++nj) {
            int off = (wc + nj * 16 + frow) * 32 + fk;
            bh[nj] = *(const s16x8*)(Bh + off);
            bl[nj] = *(const s16x8*)(Bl + off);
        }
#pragma unroll
        for (int mi = 0; mi < 4; ++mi)
#pragma unroll
            for (int nj = 0; nj < 4; ++nj) {
                acc[mi][nj] = __builtin_amdgcn_mfma_f32_16x16x32_bf16(ah[mi], bh[nj], acc[mi][nj], 0, 0, 0);
                acc[mi][nj] = __builtin_amdgcn_mfma_f32_16x16x32_bf16(ah[mi], bl[nj], acc[mi][nj], 0, 0, 0);
                acc[mi][nj] = __builtin_amdgcn_mfma_f32_16x16x32_bf16(al[mi], bh[nj], acc[mi][nj], 0, 0, 0);
            }
    }

    // D: col = lane&15, row = (lane>>4)*4 + r   [m89-verified]
    const int crow = (lane >> 4) * 4;
    const int ccol = lane & 15;
#pragma unroll
    for (int mi = 0; mi < 4; ++mi)
#pragma unroll
        for (int r = 0; r < 4; ++r) {
            float* cp = C + (size_t)(m0 + wr + mi * 16 + crow + r) * N + n0 + wc + ccol;
#pragma unroll
            for (int nj = 0; nj < 4; ++nj)
                cp[nj * 16] = acc[mi][nj][r];
        }
}

// ---------------------------------------------------------------------------
// RMSNorm + scale + RoPE, one wave per (token, head); writes bf16 hi/lo.
// prescale folds the attention 1/sqrt(hd)=0.125 (exact pow2) into Q.
// ---------------------------------------------------------------------------
__global__ __launch_bounds__(256) void rmsrope_split(const float* __restrict__ src,
                                                     const float* __restrict__ scale,
                                                     const float* __restrict__ fcos,
                                                     const float* __restrict__ fsin,
                                                     int nheads, int rowstride,
                                                     ushort* __restrict__ dh,
                                                     ushort* __restrict__ dl,
                                                     float prescale) {
    const int wid   = blockIdx.x * 4 + (threadIdx.x >> 6);
    const int lane  = threadIdx.x & 63;
    const int token = wid / nheads;
    const int h     = wid - token * nheads;
    const int s     = token & (S_LEN - 1);

    const size_t idx = (size_t)token * rowstride + h * HD + lane;
    float v = src[idx];

    float ss = v * v;
#pragma unroll
    for (int off = 32; off; off >>= 1) ss += __shfl_xor(ss, off);

    float y = v * (1.0f / sqrtf(ss * (1.0f / 64.0f) + 1e-6f)) * scale[lane];

    const int j = lane >> 1;
    float c  = fcos[s * (HD / 2) + j];
    float sn = fsin[s * (HD / 2) + j];
    float partner = __shfl_xor(y, 1);
    float o = (lane & 1) ? fmaf(partner, sn, y * c)    // im' = re*sin + im*cos
                         : fmaf(y, c, -partner * sn);  // re' = re*cos - im*sin
    o *= prescale;

    ushort hb = f2bf(o);
    dh[idx] = hb;
    dl[idx] = f2bf(o - bf2f(hb));
}

// ---------------------------------------------------------------------------
// V transpose + split: xv[token][kvh*64+d] -> vh/vl[(b*8+kvh)*64+d][s] bf16.
// Padded 64x65 fp32 LDS tile (conflict-free transpose).
// ---------------------------------------------------------------------------
__global__ __launch_bounds__(256) void vtrans(const float* __restrict__ xv,
                                              ushort* __restrict__ vh,
                                              ushort* __restrict__ vl) {
    __shared__ float T[64][65];
    const int tid = threadIdx.x;
    const int st  = blockIdx.x;        // s-tile
    const int bk  = blockIdx.y;        // b*8 + kvh
    const int b   = bk >> 3, kvh = bk & 7;

    const int r = tid >> 2, cq = (tid & 3) * 16;
    const float* src = xv + (size_t)(b * S_LEN + st * 64 + r) * KVDIM + kvh * HD + cq;
#pragma unroll
    for (int i = 0; i < 4; ++i) {
        float4 f = *(const float4*)(src + 4 * i);
        T[r][cq + 4 * i + 0] = f.x; T[r][cq + 4 * i + 1] = f.y;
        T[r][cq + 4 * i + 2] = f.z; T[r][cq + 4 * i + 3] = f.w;
    }
    __syncthreads();

    const int d = tid >> 2, sq = (tid & 3) * 16;
    s16x8 hv[2], lv[2];
#pragma unroll
    for (int half = 0; half < 2; ++half)
#pragma unroll
        for (int j = 0; j < 8; ++j) {
            float f = T[sq + half * 8 + j][d];
            ushort hb = f2bf(f);
            hv[half][j] = (short)hb;
            lv[half][j] = (short)f2bf(f - bf2f(hb));
        }
    ushort* oh = vh + (size_t)(bk * HD + d) * S_LEN + st * 64 + sq;
    ushort* ol = vl + (size_t)(bk * HD + d) * S_LEN + st * 64 + sq;
    *(s16x8*)(oh) = hv[0]; *(s16x8*)(oh + 8) = hv[1];
    *(s16x8*)(ol) = lv[0]; *(s16x8*)(ol + 8) = lv[1];
}

// ---------------------------------------------------------------------------
// MFMA causal flash attention, GQA (head h -> KV head h/4), split-bf16
// QK^T (6 MFMA) and PV (6 MFMA). 256 thr = 4 waves. QBLK=128 (32 q-rows
// per wave, Q frags hoisted from global into regs). KVBLK=64.
// Causal balance: block bx handles the complementary q-tile pair
// {bx, 15-bx} -> uniform 34 KV-steps per block; grid (8,64) = 2/CU.
// LDS: K/V tiles + per-wave P, stride 72 elems (144 B): all b128 frag
// reads land 8 dwords/bank (BW floor); staging writes 2-way. 72 KiB.
// ---------------------------------------------------------------------------
__global__ __launch_bounds__(256) void flash_attn(const ushort* __restrict__ qh_g,
                                                  const ushort* __restrict__ ql_g,
                                                  const ushort* __restrict__ kh_g,
                                                  const ushort* __restrict__ kl_g,
                                                  const ushort* __restrict__ vh_g,
                                                  const ushort* __restrict__ vl_g,
                                                  float* __restrict__ ao) {
    __shared__ ushort Kh[64 * 72];
    __shared__ ushort Kl[64 * 72];
    __shared__ ushort Vh[64 * 72];      // [d][k], pre-transposed in vh_g
    __shared__ ushort Vl[64 * 72];
    __shared__ ushort Ph[4][32 * 72];   // per-wave P hi
    __shared__ ushort Pl[4][32 * 72];   // per-wave P lo

    const int tid    = threadIdx.x;
    const int w      = tid >> 6;
    const int lanelo = tid & 15;
    const int g      = (tid >> 4) & 3;
    const int bh     = blockIdx.y;
    const int b      = bh >> 5;
    const int h      = bh & 31;
    const int kvh    = h >> 2;

    const int srow = tid >> 2;          // staging row (key or d) 0..63
    const int sh   = (tid & 3) * 16;    // staging col 0,16,32,48

    const ushort* kbh = kh_g + (size_t)(b * S_LEN) * KVDIM + kvh * HD;
    const ushort* kbl = kl_g + (size_t)(b * S_LEN) * KVDIM + kvh * HD;
    const ushort* vbh = vh_g + (size_t)((b * NKV + kvh) * HD) * S_LEN;
    const ushort* vbl = vl_g + (size_t)((b * NKV + kvh) * HD) * S_LEN;

#pragma unroll 1
    for (int sub = 0; sub < 2; ++sub) {
        const int qt  = sub ? (15 - blockIdx.x) : blockIdx.x;
        const int q0  = qt * 128;
        const int nkt = 2 * qt + 2;

        // ---- Q fragments straight from global (rows q0+32w+16mi+lanelo) ----
        s16x8 qfh[2][2], qfl[2][2];
#pragma unroll
        for (int mi = 0; mi < 2; ++mi) {
            const size_t qoff = (size_t)(b * S_LEN + q0 + 32 * w + 16 * mi + lanelo) * DMODEL
                              + h * HD + 8 * g;
            qfh[mi][0] = *(const s16x8*)(qh_g + qoff);
            qfh[mi][1] = *(const s16x8*)(qh_g + qoff + 32);
            qfl[mi][0] = *(const s16x8*)(ql_g + qoff);
            qfl[mi][1] = *(const s16x8*)(ql_g + qoff + 32);
        }

        // ---- prefetch KV tile 0 ----
        s16x8 rkh0, rkh1, rkl0, rkl1, rvh0, rvh1, rvl0, rvl1;
        {
            const size_t ko = (size_t)srow * KVDIM + sh;
            const size_t vo = (size_t)srow * S_LEN + sh;
            rkh0 = *(const s16x8*)(kbh + ko);  rkh1 = *(const s16x8*)(kbh + ko + 8);
            rkl0 = *(const s16x8*)(kbl + ko);  rkl1 = *(const s16x8*)(kbl + ko + 8);
            rvh0 = *(const s16x8*)(vbh + vo);  rvh1 = *(const s16x8*)(vbh + vo + 8);
            rvl0 = *(const s16x8*)(vbl + vo);  rvl1 = *(const s16x8*)(vbl + vo + 8);
        }

        float m_[2][4], l_[2][4];
        f32x4 O[2][4] = {};
#pragma unroll
        for (int mi = 0; mi < 2; ++mi)
#pragma unroll
            for (int r = 0; r < 4; ++r) { m_[mi][r] = -1e30f; l_[mi][r] = 0.0f; }

        for (int kt = 0; kt < nkt; ++kt) {
            __syncthreads();   // previous step done reading K/V LDS
            const int lo = srow * 72 + sh;
            *(s16x8*)(Kh + lo) = rkh0;  *(s16x8*)(Kh + lo + 8) = rkh1;
            *(s16x8*)(Kl + lo) = rkl0;  *(s16x8*)(Kl + lo + 8) = rkl1;
            *(s16x8*)(Vh + lo) = rvh0;  *(s16x8*)(Vh + lo + 8) = rvh1;
            *(s16x8*)(Vl + lo) = rvl0;  *(s16x8*)(Vl + lo + 8) = rvl1;
            if (kt + 1 < nkt) {   // prefetch next tile under compute
                const size_t ko = (size_t)((kt + 1) * 64 + srow) * KVDIM + sh;
                const size_t vo = (size_t)srow * S_LEN + (kt + 1) * 64 + sh;
                rkh0 = *(const s16x8*)(kbh + ko);  rkh1 = *(const s16x8*)(kbh + ko + 8);
                rkl0 = *(const s16x8*)(kbl + ko);  rkl1 = *(const s16x8*)(kbl + ko + 8);
                rvh0 = *(const s16x8*)(vbh + vo);  rvh1 = *(const s16x8*)(vbh + vo + 8);
                rvl0 = *(const s16x8*)(vbl + vo);  rvl1 = *(const s16x8*)(vbl + vo + 8);
            }
            __syncthreads();

            // ---- QK^T: s[mi][n][r] = S[q=q0+32w+16mi+4g+r][key=kt*64+16n+lanelo] ----
            f32x4 sc[2][4] = {};
#pragma unroll
            for (int n = 0; n < 4; ++n) {
                const int off = (16 * n + lanelo) * 72 + 8 * g;
                s16x8 kh0 = *(const s16x8*)(Kh + off), kh1 = *(const s16x8*)(Kh + off + 32);
                s16x8 kl0 = *(const s16x8*)(Kl + off), kl1 = *(const s16x8*)(Kl + off + 32);
#pragma unroll
                for (int mi = 0; mi < 2; ++mi) {
                    sc[mi][n] = __builtin_amdgcn_mfma_f32_16x16x32_bf16(qfh[mi][0], kh0, sc[mi][n], 0, 0, 0);
                    sc[mi][n] = __builtin_amdgcn_mfma_f32_16x16x32_bf16(qfh[mi][1], kh1, sc[mi][n], 0, 0, 0);
                    sc[mi][n] = __builtin_amdgcn_mfma_f32_16x16x32_bf16(qfh[mi][0], kl0, sc[mi][n], 0, 0, 0);
                    sc[mi][n] = __builtin_amdgcn_mfma_f32_16x16x32_bf16(qfh[mi][1], kl1, sc[mi][n], 0, 0, 0);
                    sc[mi][n] = __builtin_amdgcn_mfma_f32_16x16x32_bf16(qfl[mi][0], kh0, sc[mi][n], 0, 0, 0);
                    sc[mi][n] = __builtin_amdgcn_mfma_f32_16x16x32_bf16(qfl[mi][1], kh1, sc[mi][n], 0, 0, 0);
                }
            }

            // ---- causal mask (only the last two KV-steps can cross the diagonal) ----
            if (kt >= 2 * qt) {
#pragma unroll
                for (int mi = 0; mi < 2; ++mi)
#pragma unroll
                    for (int n = 0; n < 4; ++n) {
                        const int key = kt * 64 + 16 * n + lanelo;
                        const int qrow = q0 + 32 * w + 16 * mi + 4 * g;
#pragma unroll
                        for (int r = 0; r < 4; ++r)
                            if (key > qrow + r) sc[mi][n][r] = -1e30f;
                    }
            }

            // ---- online softmax (reduce over the 16 lanes of group g) ----
#pragma unroll
            for (int mi = 0; mi < 2; ++mi)
#pragma unroll
                for (int r = 0; r < 4; ++r) {
                    float mx = fmaxf(fmaxf(sc[mi][0][r], sc[mi][1][r]),
                                     fmaxf(sc[mi][2][r], sc[mi][3][r]));
#pragma unroll
                    for (int off = 1; off < 16; off <<= 1) mx = fmaxf(mx, __shfl_xor(mx, off));
                    float mnew = fmaxf(m_[mi][r], mx);
                    float corr = __expf(m_[mi][r] - mnew);
                    float ps = 0.f;
#pragma unroll
                    for (int n = 0; n < 4; ++n) {
                        float p = __expf(sc[mi][n][r] - mnew);
                        ushort phb = f2bf(p);
                        const int po = (16 * mi + 4 * g + r) * 72 + 16 * n + lanelo;
                        Ph[w][po] = phb;
                        Pl[w][po] = f2bf(p - bf2f(phb));
                        ps += p;
                    }
#pragma unroll
                    for (int off = 1; off < 16; off <<= 1) ps += __shfl_xor(ps, off);
                    l_[mi][r] = l_[mi][r] * corr + ps;
                    m_[mi][r] = mnew;
#pragma unroll
                    for (int n = 0; n < 4; ++n) O[mi][n][r] *= corr;
                }
            // P is wave-private: same-wave DS ordering suffices (no barrier)

            // ---- PV: O[mi][n] += (Ph+Pl)[q][k] * (Vh+Vl)[k][d] ----
            s16x8 pf[2][4];   // [mi][{h0,h1,l0,l1}]
#pragma unroll
            for (int mi = 0; mi < 2; ++mi) {
                const int po = (16 * mi + lanelo) * 72 + 8 * g;
                pf[mi][0] = *(const s16x8*)(Ph[w] + po);
                pf[mi][1] = *(const s16x8*)(Ph[w] + po + 32);
                pf[mi][2] = *(const s16x8*)(Pl[w] + po);
                pf[mi][3] = *(const s16x8*)(Pl[w] + po + 32);
            }
#pragma unroll
            for (int n = 0; n < 4; ++n) {
                const int vo = (16 * n + lanelo) * 72 + 8 * g;
                s16x8 vh0 = *(const s16x8*)(Vh + vo), vh1 = *(const s16x8*)(Vh + vo + 32);
                s16x8 vl0 = *(const s16x8*)(Vl + vo), vl1 = *(const s16x8*)(Vl + vo + 32);
#pragma unroll
                for (int mi = 0; mi < 2; ++mi) {
                    O[mi][n] = __builtin_amdgcn_mfma_f32_16x16x32_bf16(pf[mi][0], vh0, O[mi][n], 0, 0, 0);
                    O[mi][n] = __builtin_amdgcn_mfma_f32_16x16x32_bf16(pf[mi][1], vh1, O[mi][n], 0, 0, 0);
                    O[mi][n] = __builtin_amdgcn_mfma_f32_16x16x32_bf16(pf[mi][0], vl0, O[mi][n], 0, 0, 0);
                    O[mi][n] = __builtin_amdgcn_mfma_f32_16x16x32_bf16(pf[mi][1], vl1, O[mi][n], 0, 0, 0);
                    O[mi][n] = __builtin_amdgcn_mfma_f32_16x16x32_bf16(pf[mi][2], vh0, O[mi][n], 0, 0, 0);
                    O[mi][n] = __builtin_amdgcn_mfma_f32_16x16x32_bf16(pf[mi][3], vh1, O[mi][n], 0, 0, 0);
                }
            }
        }

        // ---- epilogue ----
#pragma unroll
        for (int mi = 0; mi < 2; ++mi)
#pragma unroll
            for (int n = 0; n < 4; ++n)
#pragma unroll
                for (int r = 0; r < 4; ++r) {
                    const int q = q0 + 32 * w + 16 * mi + 4 * g + r;
                    ao[(size_t)(b * S_LEN + q) * DMODEL + h * HD + 16 * n + lanelo] =
                        O[mi][n][r] / l_[mi][r];
                }
    }
}

// ---------------------------------------------------------------------------
extern "C" void kernel_launch(void* const* d_in, const int* in_sizes, int n_in,
                              void* d_out, int out_size, void* d_ws, size_t ws_size,
                              hipStream_t stream) {
    const float* x  = (const float*)d_in[0];
    const float* fc = (const float*)d_in[1];
    const float* fs = (const float*)d_in[2];
    const float* wq = (const float*)d_in[3];
    const float* wk = (const float*)d_in[4];
    const float* wv = (const float*)d_in[5];
    const float* wo = (const float*)d_in[6];
    const float* qs = (const float*)d_in[7];
    const float* ks = (const float*)d_in[8];
    float* out = (float*)d_out;

    // ---- workspace layout (168 MB total) ----
    char* p = (char*)d_ws;
    auto take = [&](size_t bytes) { char* r = p; p += bytes; return r; };
    ushort* wqh = (ushort*)take(8388608);   ushort* wql = (ushort*)take(8388608);
    ushort* wkh = (ushort*)take(2097152);   ushort* wkl = (ushort*)take(2097152);
    ushort* wvh = (ushort*)take(2097152);   ushort* wvl = (ushort*)take(2097152);
    ushort* woh = (ushort*)take(8388608);   ushort* wol = (ushort*)take(8388608);
    ushort* xh  = (ushort*)take(16777216);  ushort* xl  = (ushort*)take(16777216);
    float*  xq32 = (float*)take(33554432);
    float*  xk32 = (float*)take(8388608);
    float*  xv32 = (float*)take(8388608);
    ushort* qh  = (ushort*)take(16777216);  ushort* ql  = (ushort*)take(16777216);
    ushort* kh  = (ushort*)take(4194304);   ushort* kl  = (ushort*)take(4194304);
    ushort* vth = (ushort*)take(4194304);   ushort* vtl = (ushort*)take(4194304);
    // dead-after-use regions reused:
    ushort* aoh = xh;                       // xh/xl free after QKV GEMMs
    ushort* aol = xl;
    float*  ao32 = xq32;                    // xq32 free after rmsrope_split

    // ---- split inputs once ----
    csplit<<<4096, 256, 0, stream>>>(x,  xh,  xl,  1048576);
    csplit<<<2048, 256, 0, stream>>>(wq, wqh, wql, 524288);
    csplit<<<512,  256, 0, stream>>>(wk, wkh, wkl, 131072);
    csplit<<<512,  256, 0, stream>>>(wv, wvh, wvl, 131072);
    csplit<<<2048, 256, 0, stream>>>(wo, woh, wol, 524288);

    // ---- QKV projections ----
    gemm_bs<<<dim3(16, 32), 256, 0, stream>>>(xh, xl, wqh, wql, xq32, MTOK, DMODEL, DMODEL);
    gemm_bs<<<dim3(4,  32), 256, 0, stream>>>(xh, xl, wkh, wkl, xk32, MTOK, KVDIM,  DMODEL);
    gemm_bs<<<dim3(4,  32), 256, 0, stream>>>(xh, xl, wvh, wvl, xv32, MTOK, KVDIM,  DMODEL);

    // ---- RMSNorm+RoPE -> split bf16 (Q pre-scaled by 0.125); V transpose+split ----
    rmsrope_split<<<MTOK * NHEADS / 4, 256, 0, stream>>>(xq32, qs, fc, fs, NHEADS, DMODEL, qh, ql, 0.125f);
    rmsrope_split<<<MTOK * NKV / 4,    256, 0, stream>>>(xk32, ks, fc, fs, NKV,    KVDIM,  kh, kl, 1.0f);
    vtrans<<<dim3(32, 16), 256, 0, stream>>>(xv32, vth, vtl);

    // ---- causal GQA flash attention (paired q-tiles for balance) ----
    flash_attn<<<dim3(8, 64), 256, 0, stream>>>(qh, ql, kh, kl, vth, vtl, ao32);

    // ---- output projection ----
    csplit<<<4096, 256, 0, stream>>>(ao32, aoh, aol, 1048576);
    gemm_bs<<<dim3(16, 32), 256, 0, stream>>>(aoh, aol, woh, wol, out, MTOK, DMODEL, DMODEL);
}

// Round 9
// 649.539 us; speedup vs baseline: 1.0690x; 1.0690x over previous
//
#include <hip/hip_runtime.h>
#include <hip/hip_bf16.h>
#include <math.h>

// Problem constants (B=2, S=2048, D=2048, 32 heads / 8 KV heads, hd=64)
#define S_LEN   2048
#define DMODEL  2048
#define NHEADS  32
#define NKV     8
#define HD      64
#define MTOK    4096   // B * S
#define KVDIM   512    // NKV * HD

typedef short s16x8 __attribute__((ext_vector_type(8)));  // 8 bf16 (doc-verified MFMA frag type)
typedef float f32x4 __attribute__((ext_vector_type(4)));

// bf16 bit helpers
__device__ __forceinline__ ushort f2bf(float f) {          // RNE
    union { float f; uint u; } a; a.f = f;
    return (ushort)((a.u + 0x7fffu + ((a.u >> 16) & 1u)) >> 16);
}
__device__ __forceinline__ float bf2f(ushort h) {
    union { uint u; float f; } a; a.u = ((uint)h) << 16; return a.f;
}

// async global->LDS, 16B per lane. lds base must be WAVE-UNIFORM; HW places
// lane i at lds + 16*i. [m03/m97-verified pattern]
__device__ __forceinline__ void gload16(const void* g, void* l) {
    __builtin_amdgcn_global_load_lds(
        (const __attribute__((address_space(1))) void*)g,
        (__attribute__((address_space(3))) void*)l, 16, 0, 0);
}

// ---------------------------------------------------------------------------
// Elementwise fp32 -> bf16 hi + bf16 lo (exact residual, RNE). 8 elems/thread.
// ---------------------------------------------------------------------------
__global__ __launch_bounds__(256) void csplit(const float* __restrict__ src,
                                              ushort* __restrict__ dh,
                                              ushort* __restrict__ dl, int n8) {
    const int i = blockIdx.x * 256 + threadIdx.x;
    if (i >= n8) return;
    float4 a = ((const float4*)src)[2 * i];
    float4 b = ((const float4*)src)[2 * i + 1];
    float f[8] = {a.x, a.y, a.z, a.w, b.x, b.y, b.z, b.w};
    s16x8 h, l;
#pragma unroll
    for (int j = 0; j < 8; ++j) {
        ushort hb = f2bf(f[j]);
        h[j] = (short)hb;
        l[j] = (short)f2bf(f[j] - bf2f(hb));
    }
    ((s16x8*)dh)[i] = h;
    ((s16x8*)dl)[i] = l;
}

// ---------------------------------------------------------------------------
// Split-precision MFMA GEMM on pre-split operands:
// C[M,N](fp32) = (Ah+Al)[M,K] @ (Bh+Bl)[N,K]^T ~= AhBh + AhBl + AlBh.
// 128x128 tile, BK=32, 4 waves (2x2), 64x64/wave. Staging via
// global_load_lds width-16 (m97 2-barrier structure); LDS layout is
// byte-linear in tid (wave-uniform base + lane*16) as the HW requires.
// ---------------------------------------------------------------------------
__global__ __launch_bounds__(256) void gemm_bs(const ushort* __restrict__ Ahg,
                                               const ushort* __restrict__ Alg,
                                               const ushort* __restrict__ Bhg,
                                               const ushort* __restrict__ Blg,
                                               float* __restrict__ C,
                                               int M, int N, int K) {
    __shared__ ushort Ah[128 * 32];
    __shared__ ushort Al[128 * 32];
    __shared__ ushort Bh[128 * 32];
    __shared__ ushort Bl[128 * 32];

    const int tid  = threadIdx.x;
    const int wave = tid >> 6;
    const int lane = tid & 63;
    const int wr   = (wave >> 1) * 64;
    const int wc   = (wave & 1) * 64;
    const int m0   = blockIdx.y * 128;
    const int n0   = blockIdx.x * 128;

    const int srow = tid >> 2;          // 0..63
    const int skq  = (tid & 3) * 8;     // k-octet 0,8,16,24

    const ushort* pAh = Ahg + (size_t)(m0 + srow) * K + skq;
    const ushort* pAl = Alg + (size_t)(m0 + srow) * K + skq;
    const ushort* pBh = Bhg + (size_t)(n0 + srow) * K + skq;
    const ushort* pBl = Blg + (size_t)(n0 + srow) * K + skq;
    const size_t r64 = (size_t)64 * K;

    // wave-uniform LDS staging bases (elem offset tid*8 = byte tid*16: linear)
    ushort* const lA0  = Ah + wave * 512;  ushort* const lA1  = Ah + 64 * 32 + wave * 512;
    ushort* const lAl0 = Al + wave * 512;  ushort* const lAl1 = Al + 64 * 32 + wave * 512;
    ushort* const lB0  = Bh + wave * 512;  ushort* const lB1  = Bh + 64 * 32 + wave * 512;
    ushort* const lBl0 = Bl + wave * 512;  ushort* const lBl1 = Bl + 64 * 32 + wave * 512;

    const int frow = lane & 15;
    const int fk   = (lane >> 4) * 8;

    f32x4 acc[4][4] = {};

    for (int k0 = 0; k0 < K; k0 += 32) {
        __syncthreads();   // all waves done reading previous tile
        gload16(pAh + k0, lA0);        gload16(pAh + r64 + k0, lA1);
        gload16(pAl + k0, lAl0);       gload16(pAl + r64 + k0, lAl1);
        gload16(pBh + k0, lB0);        gload16(pBh + r64 + k0, lB1);
        gload16(pBl + k0, lBl0);       gload16(pBl + r64 + k0, lBl1);
        __syncthreads();   // compiler drains vmcnt before barrier -> LDS valid

        s16x8 ah[4], al[4], bh[4], bl[4];
#pragma unroll
        for (int mi = 0; mi < 4; ++mi) {
            int off = (wr + mi * 16 + frow) * 32 + fk;
            ah[mi] = *(const s16x8*)(Ah + off);
            al[mi] = *(const s16x8*)(Al + off);
        }
#pragma unroll
        for (int nj = 0; nj < 4; ++nj) {
            int off = (wc + nj * 16 + frow) * 32 + fk;
            bh[nj] = *(const s16x8*)(Bh + off);
            bl[nj] = *(const s16x8*)(Bl + off);
        }
#pragma unroll
        for (int mi = 0; mi < 4; ++mi)
#pragma unroll
            for (int nj = 0; nj < 4; ++nj) {
                acc[mi][nj] = __builtin_amdgcn_mfma_f32_16x16x32_bf16(ah[mi], bh[nj], acc[mi][nj], 0, 0, 0);
                acc[mi][nj] = __builtin_amdgcn_mfma_f32_16x16x32_bf16(ah[mi], bl[nj], acc[mi][nj], 0, 0, 0);
                acc[mi][nj] = __builtin_amdgcn_mfma_f32_16x16x32_bf16(al[mi], bh[nj], acc[mi][nj], 0, 0, 0);
            }
    }

    // D: col = lane&15, row = (lane>>4)*4 + r   [m89-verified]
    const int crow = (lane >> 4) * 4;
    const int ccol = lane & 15;
#pragma unroll
    for (int mi = 0; mi < 4; ++mi)
#pragma unroll
        for (int r = 0; r < 4; ++r) {
            float* cp = C + (size_t)(m0 + wr + mi * 16 + crow + r) * N + n0 + wc + ccol;
#pragma unroll
            for (int nj = 0; nj < 4; ++nj)
                cp[nj * 16] = acc[mi][nj][r];
        }
}

// ---------------------------------------------------------------------------
// RMSNorm + scale + RoPE, one wave per (token, head); writes bf16 hi/lo.
// Separate in/out row strides so it can read the fused KV projection output.
// ---------------------------------------------------------------------------
__global__ __launch_bounds__(256) void rmsrope_split(const float* __restrict__ src,
                                                     const float* __restrict__ scale,
                                                     const float* __restrict__ fcos,
                                                     const float* __restrict__ fsin,
                                                     int nheads, int instride, int outstride,
                                                     ushort* __restrict__ dh,
                                                     ushort* __restrict__ dl,
                                                     float prescale) {
    const int wid   = blockIdx.x * 4 + (threadIdx.x >> 6);
    const int lane  = threadIdx.x & 63;
    const int token = wid / nheads;
    const int h     = wid - token * nheads;
    const int s     = token & (S_LEN - 1);

    float v = src[(size_t)token * instride + h * HD + lane];

    float ss = v * v;
#pragma unroll
    for (int off = 32; off; off >>= 1) ss += __shfl_xor(ss, off);

    float y = v * (1.0f / sqrtf(ss * (1.0f / 64.0f) + 1e-6f)) * scale[lane];

    const int j = lane >> 1;
    float c  = fcos[s * (HD / 2) + j];
    float sn = fsin[s * (HD / 2) + j];
    float partner = __shfl_xor(y, 1);
    float o = (lane & 1) ? fmaf(partner, sn, y * c)    // im' = re*sin + im*cos
                         : fmaf(y, c, -partner * sn);  // re' = re*cos - im*sin
    o *= prescale;

    const size_t oidx = (size_t)token * outstride + h * HD + lane;
    ushort hb = f2bf(o);
    dh[oidx] = hb;
    dl[oidx] = f2bf(o - bf2f(hb));
}

// ---------------------------------------------------------------------------
// V transpose + split: src[token][kvh*64+d] (stride instride) ->
// vh/vl[(b*8+kvh)*64+d][s] bf16. Padded 64x65 fp32 LDS tile.
// ---------------------------------------------------------------------------
__global__ __launch_bounds__(256) void vtrans(const float* __restrict__ xv,
                                              int instride,
                                              ushort* __restrict__ vh,
                                              ushort* __restrict__ vl) {
    __shared__ float T[64][65];
    const int tid = threadIdx.x;
    const int st  = blockIdx.x;        // s-tile
    const int bk  = blockIdx.y;        // b*8 + kvh
    const int b   = bk >> 3, kvh = bk & 7;

    const int r = tid >> 2, cq = (tid & 3) * 16;
    const float* src = xv + (size_t)(b * S_LEN + st * 64 + r) * instride + kvh * HD + cq;
#pragma unroll
    for (int i = 0; i < 4; ++i) {
        float4 f = *(const float4*)(src + 4 * i);
        T[r][cq + 4 * i + 0] = f.x; T[r][cq + 4 * i + 1] = f.y;
        T[r][cq + 4 * i + 2] = f.z; T[r][cq + 4 * i + 3] = f.w;
    }
    __syncthreads();

    const int d = tid >> 2, sq = (tid & 3) * 16;
    s16x8 hv[2], lv[2];
#pragma unroll
    for (int half = 0; half < 2; ++half)
#pragma unroll
        for (int j = 0; j < 8; ++j) {
            float f = T[sq + half * 8 + j][d];
            ushort hb = f2bf(f);
            hv[half][j] = (short)hb;
            lv[half][j] = (short)f2bf(f - bf2f(hb));
        }
    ushort* oh = vh + (size_t)(bk * HD + d) * S_LEN + st * 64 + sq;
    ushort* ol = vl + (size_t)(bk * HD + d) * S_LEN + st * 64 + sq;
    *(s16x8*)(oh) = hv[0]; *(s16x8*)(oh + 8) = hv[1];
    *(s16x8*)(ol) = lv[0]; *(s16x8*)(ol + 8) = lv[1];
}

// ---------------------------------------------------------------------------
// MFMA causal flash attention, GQA, split-bf16 QK^T and PV.
// 256 thr = 4 waves; QBLK=128 (32 q/wave); KVBLK=64; paired q-tiles
// {bx, 15-bx} for causal balance. P split via TRUNCATION (4 VALU/elem;
// R6 profile: VALUBusy 42% vs MfmaUtil 21% with RNE splits on the VALU
// critical path). Epilogue writes split bf16 directly (fused csplit).
// ---------------------------------------------------------------------------
__global__ __launch_bounds__(256) void flash_attn(const ushort* __restrict__ qh_g,
                                                  const ushort* __restrict__ ql_g,
                                                  const ushort* __restrict__ kh_g,
                                                  const ushort* __restrict__ kl_g,
                                                  const ushort* __restrict__ vh_g,
                                                  const ushort* __restrict__ vl_g,
                                                  ushort* __restrict__ aoh,
                                                  ushort* __restrict__ aol) {
    __shared__ ushort Kh[64 * 72];
    __shared__ ushort Kl[64 * 72];
    __shared__ ushort Vh[64 * 72];      // [d][k], pre-transposed in vh_g
    __shared__ ushort Vl[64 * 72];
    __shared__ ushort Ph[4][32 * 72];   // per-wave P hi
    __shared__ ushort Pl[4][32 * 72];   // per-wave P lo

    const int tid    = threadIdx.x;
    const int w      = tid >> 6;
    const int lanelo = tid & 15;
    const int g      = (tid >> 4) & 3;
    const int bh     = blockIdx.y;
    const int b      = bh >> 5;
    const int h      = bh & 31;
    const int kvh    = h >> 2;

    const int srow = tid >> 2;          // staging row (key or d) 0..63
    const int sh   = (tid & 3) * 16;    // staging col 0,16,32,48

    const ushort* kbh = kh_g + (size_t)(b * S_LEN) * KVDIM + kvh * HD;
    const ushort* kbl = kl_g + (size_t)(b * S_LEN) * KVDIM + kvh * HD;
    const ushort* vbh = vh_g + (size_t)((b * NKV + kvh) * HD) * S_LEN;
    const ushort* vbl = vl_g + (size_t)((b * NKV + kvh) * HD) * S_LEN;

    ushort* const Phw = Ph[w];
    ushort* const Plw = Pl[w];

#pragma unroll 1
    for (int sub = 0; sub < 2; ++sub) {
        const int qt  = sub ? (15 - blockIdx.x) : blockIdx.x;
        const int q0  = qt * 128;
        const int nkt = 2 * qt + 2;

        // ---- Q fragments straight from global (rows q0+32w+16mi+lanelo) ----
        s16x8 qfh[2][2], qfl[2][2];
#pragma unroll
        for (int mi = 0; mi < 2; ++mi) {
            const size_t qoff = (size_t)(b * S_LEN + q0 + 32 * w + 16 * mi + lanelo) * DMODEL
                              + h * HD + 8 * g;
            qfh[mi][0] = *(const s16x8*)(qh_g + qoff);
            qfh[mi][1] = *(const s16x8*)(qh_g + qoff + 32);
            qfl[mi][0] = *(const s16x8*)(ql_g + qoff);
            qfl[mi][1] = *(const s16x8*)(ql_g + qoff + 32);
        }

        // ---- prefetch KV tile 0 ----
        s16x8 rkh0, rkh1, rkl0, rkl1, rvh0, rvh1, rvl0, rvl1;
        {
            const size_t ko = (size_t)srow * KVDIM + sh;
            const size_t vo = (size_t)srow * S_LEN + sh;
            rkh0 = *(const s16x8*)(kbh + ko);  rkh1 = *(const s16x8*)(kbh + ko + 8);
            rkl0 = *(const s16x8*)(kbl + ko);  rkl1 = *(const s16x8*)(kbl + ko + 8);
            rvh0 = *(const s16x8*)(vbh + vo);  rvh1 = *(const s16x8*)(vbh + vo + 8);
            rvl0 = *(const s16x8*)(vbl + vo);  rvl1 = *(const s16x8*)(vbl + vo + 8);
        }

        float m_[2][4], l_[2][4];
        f32x4 O[2][4] = {};
#pragma unroll
        for (int mi = 0; mi < 2; ++mi)
#pragma unroll
            for (int r = 0; r < 4; ++r) { m_[mi][r] = -1e30f; l_[mi][r] = 0.0f; }

        for (int kt = 0; kt < nkt; ++kt) {
            __syncthreads();   // previous step done reading K/V LDS
            const int lo = srow * 72 + sh;
            *(s16x8*)(Kh + lo) = rkh0;  *(s16x8*)(Kh + lo + 8) = rkh1;
            *(s16x8*)(Kl + lo) = rkl0;  *(s16x8*)(Kl + lo + 8) = rkl1;
            *(s16x8*)(Vh + lo) = rvh0;  *(s16x8*)(Vh + lo + 8) = rvh1;
            *(s16x8*)(Vl + lo) = rvl0;  *(s16x8*)(Vl + lo + 8) = rvl1;
            if (kt + 1 < nkt) {   // prefetch next tile under compute
                const size_t ko = (size_t)((kt + 1) * 64 + srow) * KVDIM + sh;
                const size_t vo = (size_t)srow * S_LEN + (kt + 1) * 64 + sh;
                rkh0 = *(const s16x8*)(kbh + ko);  rkh1 = *(const s16x8*)(kbh + ko + 8);
                rkl0 = *(const s16x8*)(kbl + ko);  rkl1 = *(const s16x8*)(kbl + ko + 8);
                rvh0 = *(const s16x8*)(vbh + vo);  rvh1 = *(const s16x8*)(vbh + vo + 8);
                rvl0 = *(const s16x8*)(vbl + vo);  rvl1 = *(const s16x8*)(vbl + vo + 8);
            }
            __syncthreads();

            // ---- QK^T ----
            f32x4 sc[2][4] = {};
#pragma unroll
            for (int n = 0; n < 4; ++n) {
                const int off = (16 * n + lanelo) * 72 + 8 * g;
                s16x8 kh0 = *(const s16x8*)(Kh + off), kh1 = *(const s16x8*)(Kh + off + 32);
                s16x8 kl0 = *(const s16x8*)(Kl + off), kl1 = *(const s16x8*)(Kl + off + 32);
#pragma unroll
                for (int mi = 0; mi < 2; ++mi) {
                    sc[mi][n] = __builtin_amdgcn_mfma_f32_16x16x32_bf16(qfh[mi][0], kh0, sc[mi][n], 0, 0, 0);
                    sc[mi][n] = __builtin_amdgcn_mfma_f32_16x16x32_bf16(qfh[mi][1], kh1, sc[mi][n], 0, 0, 0);
                    sc[mi][n] = __builtin_amdgcn_mfma_f32_16x16x32_bf16(qfh[mi][0], kl0, sc[mi][n], 0, 0, 0);
                    sc[mi][n] = __builtin_amdgcn_mfma_f32_16x16x32_bf16(qfh[mi][1], kl1, sc[mi][n], 0, 0, 0);
                    sc[mi][n] = __builtin_amdgcn_mfma_f32_16x16x32_bf16(qfl[mi][0], kh0, sc[mi][n], 0, 0, 0);
                    sc[mi][n] = __builtin_amdgcn_mfma_f32_16x16x32_bf16(qfl[mi][1], kh1, sc[mi][n], 0, 0, 0);
                }
            }

            // ---- causal mask ----
            if (kt >= 2 * qt) {
#pragma unroll
                for (int mi = 0; mi < 2; ++mi)
#pragma unroll
                    for (int n = 0; n < 4; ++n) {
                        const int key = kt * 64 + 16 * n + lanelo;
                        const int qrow = q0 + 32 * w + 16 * mi + 4 * g;
#pragma unroll
                        for (int r = 0; r < 4; ++r)
                            if (key > qrow + r) sc[mi][n][r] = -1e30f;
                    }
            }

            // ---- online softmax; P split via truncation (cheap) ----
#pragma unroll
            for (int mi = 0; mi < 2; ++mi)
#pragma unroll
                for (int r = 0; r < 4; ++r) {
                    float mx = fmaxf(fmaxf(sc[mi][0][r], sc[mi][1][r]),
                                     fmaxf(sc[mi][2][r], sc[mi][3][r]));
#pragma unroll
                    for (int off = 1; off < 16; off <<= 1) mx = fmaxf(mx, __shfl_xor(mx, off));
                    float mnew = fmaxf(m_[mi][r], mx);
                    float corr = __expf(m_[mi][r] - mnew);
                    float ps = 0.f;
#pragma unroll
                    for (int n = 0; n < 4; ++n) {
                        float p = __expf(sc[mi][n][r] - mnew);
                        uint pu = __float_as_uint(p);
                        float plo = p - __uint_as_float(pu & 0xffff0000u);
                        const int po = (16 * mi + 4 * g + r) * 72 + 16 * n + lanelo;
                        Phw[po] = (ushort)(pu >> 16);
                        Plw[po] = (ushort)(__float_as_uint(plo) >> 16);
                        ps += p;
                    }
#pragma unroll
                    for (int off = 1; off < 16; off <<= 1) ps += __shfl_xor(ps, off);
                    l_[mi][r] = l_[mi][r] * corr + ps;
                    m_[mi][r] = mnew;
#pragma unroll
                    for (int n = 0; n < 4; ++n) O[mi][n][r] *= corr;
                }
            // P is wave-private: same-wave DS ordering suffices (no barrier)

            // ---- PV: O += (Ph+Pl)(Vh+Vl), lo*lo dropped ----
            s16x8 pf[2][4];
#pragma unroll
            for (int mi = 0; mi < 2; ++mi) {
                const int po = (16 * mi + lanelo) * 72 + 8 * g;
                pf[mi][0] = *(const s16x8*)(Phw + po);
                pf[mi][1] = *(const s16x8*)(Phw + po + 32);
                pf[mi][2] = *(const s16x8*)(Plw + po);
                pf[mi][3] = *(const s16x8*)(Plw + po + 32);
            }
#pragma unroll
            for (int n = 0; n < 4; ++n) {
                const int vo = (16 * n + lanelo) * 72 + 8 * g;
                s16x8 vh0 = *(const s16x8*)(Vh + vo), vh1 = *(const s16x8*)(Vh + vo + 32);
                s16x8 vl0 = *(const s16x8*)(Vl + vo), vl1 = *(const s16x8*)(Vl + vo + 32);
#pragma unroll
                for (int mi = 0; mi < 2; ++mi) {
                    O[mi][n] = __builtin_amdgcn_mfma_f32_16x16x32_bf16(pf[mi][0], vh0, O[mi][n], 0, 0, 0);
                    O[mi][n] = __builtin_amdgcn_mfma_f32_16x16x32_bf16(pf[mi][1], vh1, O[mi][n], 0, 0, 0);
                    O[mi][n] = __builtin_amdgcn_mfma_f32_16x16x32_bf16(pf[mi][0], vl0, O[mi][n], 0, 0, 0);
                    O[mi][n] = __builtin_amdgcn_mfma_f32_16x16x32_bf16(pf[mi][1], vl1, O[mi][n], 0, 0, 0);
                    O[mi][n] = __builtin_amdgcn_mfma_f32_16x16x32_bf16(pf[mi][2], vh0, O[mi][n], 0, 0, 0);
                    O[mi][n] = __builtin_amdgcn_mfma_f32_16x16x32_bf16(pf[mi][3], vh1, O[mi][n], 0, 0, 0);
                }
            }
        }

        // ---- epilogue: write split bf16 (fused csplit for the out-proj) ----
#pragma unroll
        for (int mi = 0; mi < 2; ++mi)
#pragma unroll
            for (int n = 0; n < 4; ++n)
#pragma unroll
                for (int r = 0; r < 4; ++r) {
                    const int q = q0 + 32 * w + 16 * mi + 4 * g + r;
                    const size_t o = (size_t)(b * S_LEN + q) * DMODEL + h * HD + 16 * n + lanelo;
                    float v = O[mi][n][r] / l_[mi][r];
                    ushort hb = f2bf(v);
                    aoh[o] = hb;
                    aol[o] = f2bf(v - bf2f(hb));
                }
    }
}

// ---------------------------------------------------------------------------
extern "C" void kernel_launch(void* const* d_in, const int* in_sizes, int n_in,
                              void* d_out, int out_size, void* d_ws, size_t ws_size,
                              hipStream_t stream) {
    const float* x  = (const float*)d_in[0];
    const float* fc = (const float*)d_in[1];
    const float* fs = (const float*)d_in[2];
    const float* wq = (const float*)d_in[3];
    const float* wk = (const float*)d_in[4];
    const float* wv = (const float*)d_in[5];
    const float* wo = (const float*)d_in[6];
    const float* qs = (const float*)d_in[7];
    const float* ks = (const float*)d_in[8];
    float* out = (float*)d_out;

    // ---- workspace layout (168 MB) ----
    char* p = (char*)d_ws;
    auto take = [&](size_t bytes) { char* r = p; p += bytes; return r; };
    ushort* wqh  = (ushort*)take(8388608);   ushort* wql  = (ushort*)take(8388608);
    ushort* wkvh = (ushort*)take(4194304);   ushort* wkvl = (ushort*)take(4194304);  // [1024][2048] K rows then V rows
    ushort* woh  = (ushort*)take(8388608);   ushort* wol  = (ushort*)take(8388608);
    ushort* xh   = (ushort*)take(16777216);  ushort* xl   = (ushort*)take(16777216);
    float*  xq32  = (float*)take(33554432);
    float*  xkv32 = (float*)take(16777216);  // [4096][1024]: cols 0-511 K, 512-1023 V
    ushort* qh   = (ushort*)take(16777216);  ushort* ql   = (ushort*)take(16777216);
    ushort* kh   = (ushort*)take(4194304);   ushort* kl   = (ushort*)take(4194304);
    ushort* vth  = (ushort*)take(4194304);   ushort* vtl  = (ushort*)take(4194304);
    // xh/xl are dead after the QKV GEMMs -> reuse for split attention output
    ushort* aoh = xh;
    ushort* aol = xl;

    // ---- split inputs once (wk,wv land contiguously as rows 0-511/512-1023) ----
    csplit<<<4096, 256, 0, stream>>>(x,  xh,  xl,  1048576);
    csplit<<<2048, 256, 0, stream>>>(wq, wqh, wql, 524288);
    csplit<<<512,  256, 0, stream>>>(wk, wkvh,                wkvl,                131072);
    csplit<<<512,  256, 0, stream>>>(wv, wkvh + 512 * DMODEL, wkvl + 512 * DMODEL, 131072);
    csplit<<<2048, 256, 0, stream>>>(wo, woh, wol, 524288);

    // ---- projections: Q (N=2048) and fused KV (N=1024) ----
    gemm_bs<<<dim3(16, 32), 256, 0, stream>>>(xh, xl, wqh,  wql,  xq32,  MTOK, DMODEL, DMODEL);
    gemm_bs<<<dim3(8,  32), 256, 0, stream>>>(xh, xl, wkvh, wkvl, xkv32, MTOK, 1024,   DMODEL);

    // ---- RMSNorm+RoPE -> split bf16 (Q pre-scaled by 0.125); V transpose+split ----
    rmsrope_split<<<MTOK * NHEADS / 4, 256, 0, stream>>>(xq32, qs, fc, fs, NHEADS, DMODEL, DMODEL, qh, ql, 0.125f);
    rmsrope_split<<<MTOK * NKV / 4,    256, 0, stream>>>(xkv32, ks, fc, fs, NKV,   1024,   KVDIM,  kh, kl, 1.0f);
    vtrans<<<dim3(32, 16), 256, 0, stream>>>(xkv32 + 512, 1024, vth, vtl);

    // ---- causal GQA flash attention (epilogue writes split bf16) ----
    flash_attn<<<dim3(8, 64), 256, 0, stream>>>(qh, ql, kh, kl, vth, vtl, aoh, aol);

    // ---- output projection ----
    gemm_bs<<<dim3(16, 32), 256, 0, stream>>>(aoh, aol, woh, wol, out, MTOK, DMODEL, DMODEL);
}